// Round 8
// baseline (1329.571 us; speedup 1.0000x reference)
//
#include <hip/hip_runtime.h>
#include <hip/hip_bf16.h>
#include <stdint.h>

// GAT forward, N=8192, IN=256, OUT=128. Inputs fp32 (adj int32), output fp32.
// softmax_j(a1_i + a2_j | adj) == adj_ij*exp(a2_j)/sum_j adj_ij*exp(a2_j)  (a1 cancels)
// -> out = (adj @ (w*h)) / (adj @ w), with w=exp(h.a2w+a2b), h=F@W+b.
// v11 = ATTRIBUTION PROBE on v9. R7 measured T_agg = 24.1us (4x launch probe).
// R6 ledger: fill ~159 + hW + adjbits + 24 + epi = 431 -> hW+adjbits+epi ~= 248
// vs ~85 floor; ~160us unattributed and invisible (all kernels < 160us top-5
// cutoff). This round each suspect kernel re-executes in-kernel (adjbits x8,
// hW x16, epi x16; outputs identical; per-rep asm-opaque pointers block
// CSE/DSE) so each surfaces in top-5 WITH counters; dur/REP = T. k_agg x1.
//   Expected total ~= 431 + 7*T_adj + 15*(T_hW + T_epi).

typedef __attribute__((ext_vector_type(8))) short short8;
typedef __attribute__((ext_vector_type(4))) float float4v;

static __device__ __forceinline__ unsigned short f2bf(float f) {
    union { float f; uint32_t i; } v; v.f = f;
    uint32_t r = v.i + 0x7FFFu + ((v.i >> 16) & 1u);
    return (unsigned short)(r >> 16);
}

// round fp32 to bf16 precision, keep as fp32 (matches MFMA-bf16 numerics)
static __device__ __forceinline__ float bfr(float x) {
    union { float f; uint32_t u; } v; v.f = x;
    uint32_t r = (v.u + 0x7FFFu + ((v.u >> 16) & 1u)) & 0xFFFF0000u;
    union { uint32_t u; float f; } o; o.u = r;
    return o.f;
}

// expand 8 bits -> 8 packed bf16 {0.0, 1.0}.
static __device__ __forceinline__ short8 expand8(uint32_t B) {
    uint64_t S = ((uint64_t)B * 0x8040201008040201ull >> 7) & 0x0101010101010101ull;
    uint32_t lo = (uint32_t)S;          // bytes {b7,b6,b5,b4}
    uint32_t hi = (uint32_t)(S >> 32);  // bytes {b3,b2,b1,b0}
    union { uint32_t u[4]; short8 s; } r;
    r.u[0] = ((hi >> 24) | (((hi >> 16) & 0xFFu) << 16)) * 0x3F80u;  // e0,e1
    r.u[1] = (((hi >> 8) & 0xFFu) | ((hi & 0xFFu) << 16)) * 0x3F80u; // e2,e3
    r.u[2] = ((lo >> 24) | (((lo >> 16) & 0xFFu) << 16)) * 0x3F80u;  // e4,e5
    r.u[3] = (((lo >> 8) & 0xFFu) | ((lo & 0xFFu) << 16)) * 0x3F80u; // e6,e7
    return r.s;
}

// async global->LDS, 16 B per lane. LDS dest is (wave-uniform base + lane*16).
static __device__ __forceinline__ void gl_lds16(const void* g, void* l) {
    __builtin_amdgcn_global_load_lds(
        (const __attribute__((address_space(1))) uint32_t*)g,
        (__attribute__((address_space(3))) uint32_t*)l, 16, 0, 0);
}

// ---- prepass: adj int32 -> bitmask. PROBE: x8 in-kernel reps ----
__global__ __launch_bounds__(256) void k_adjbits(const int* __restrict__ adj,
                                                 uint32_t* __restrict__ adjb) {
    int t = threadIdx.x, lane = t & 63;
    int wv = blockIdx.x * 4 + (t >> 6);           // 0..16383
    int row = wv >> 1, half = wv & 1;
    #pragma unroll 1
    for (int rep = 0; rep < 8; rep++) {
        const int4* p = reinterpret_cast<const int4*>(adj + (size_t)row * 8192 + half * 4096) + lane;
        uint32_t* ob = adjb + (size_t)row * 256 + half * 128;
        asm volatile("" : "+v"(p), "+v"(ob));     // opaque: loads+stores re-execute
        #pragma unroll 4
        for (int kk = 0; kk < 16; kk++) {
            int4 v = p[kk * 64];
            uint32_t nib = (v.x != 0 ? 1u : 0u) | (v.y != 0 ? 2u : 0u) |
                           (v.z != 0 ? 4u : 0u) | (v.w != 0 ? 8u : 0u);
            uint32_t q = nib | (((uint32_t)__shfl_xor((int)nib, 1)) << 4);
            q |= ((uint32_t)__shfl_xor((int)q, 2)) << 8;
            q |= ((uint32_t)__shfl_xor((int)q, 4)) << 16;
            if ((lane & 7) == 0) ob[kk * 8 + (lane >> 3)] = q;
        }
    }
}

// ---- h = F@W+b, w = exp(h.a2w+a2b), emit fragment-major whB. PROBE: x16 ----
__global__ __launch_bounds__(256) void k_hW(const float* __restrict__ F,
                                            const float* __restrict__ W,
                                            const float* __restrict__ bvec,
                                            const float* __restrict__ a2w,
                                            const float* __restrict__ a2b,
                                            unsigned short* __restrict__ whB) {
    __shared__ float Fs[32 * 256];     // 32 KB
    __shared__ float Ws[64 * 128];     // 32 KB (one kt-chunk of W)
    __shared__ float bs[128], aws[128], wls[32];
    __shared__ float ab_s;

    int t = threadIdx.x;
    int row = t >> 3, g = t & 7;
    int ig = blockIdx.x, j0 = ig * 32;

    if (t < 128) { bs[t] = bvec[t]; aws[t] = a2w[t]; }
    if (t == 0) ab_s = a2b[0];

    #pragma unroll
    for (int i = 0; i < 8; i++) {
        int flat = t + 256 * i;                   // float4 index
        int fr = flat >> 6, fp_ = (flat & 63) << 2;
        float4 v = *reinterpret_cast<const float4*>(F + (size_t)(j0 + fr) * 256 + fp_);
        float4 o; o.x = bfr(v.x); o.y = bfr(v.y); o.z = bfr(v.z); o.w = bfr(v.w);
        *reinterpret_cast<float4*>(&Fs[fr * 256 + fp_]) = o;
    }

    #pragma unroll 1
    for (int rep = 0; rep < 16; rep++) {
        const float* Wo = W;
        unsigned short* whBo = whB;
        asm volatile("" : "+v"(Wo), "+v"(whBo));  // opaque per rep
        __syncthreads();                          // prev rep's Ws readers done

        float h[16];
        #pragma unroll
        for (int i = 0; i < 16; i++) h[i] = 0.0f;

        for (int kt = 0; kt < 4; kt++) {
            if (kt) __syncthreads();
            #pragma unroll
            for (int i = 0; i < 8; i++) {
                int flat = t + 256 * i;
                int wr = flat >> 5, wp = (flat & 31) << 2;
                float4 v = *reinterpret_cast<const float4*>(Wo + (size_t)(kt * 64 + wr) * 128 + wp);
                float4 o; o.x = bfr(v.x); o.y = bfr(v.y); o.z = bfr(v.z); o.w = bfr(v.w);
                *reinterpret_cast<float4*>(&Ws[wr * 128 + wp]) = o;
            }
            __syncthreads();
            for (int kk = 0; kk < 64; kk++) {
                float f = Fs[row * 256 + kt * 64 + kk];
                #pragma unroll
                for (int i = 0; i < 16; i++)
                    h[i] += f * Ws[kk * 128 + g * 16 + i];
            }
        }

        float part = 0.0f;
        #pragma unroll
        for (int i = 0; i < 16; i++) {
            h[i] += bs[g * 16 + i];
            part += h[i] * aws[g * 16 + i];
        }
        part += __shfl_xor(part, 1);
        part += __shfl_xor(part, 2);
        part += __shfl_xor(part, 4);
        float wv = expf(fminf(fmaxf(part + ab_s, -60.0f), 60.0f));
        if (g == 0) wls[row] = wv;

        int kq = row >> 3, r = row & 7;
        #pragma unroll
        for (int i = 0; i < 16; i++) {
            unsigned short u = f2bf(h[i] * wv);
            whBo[((size_t)(ig * 9 + g) * 64 + kq * 16 + i) * 8 + r] = u;
        }
        __syncthreads();
        if (t < 64) {
            int m0 = t & 15, kq2 = t >> 4;
            uint4 val = make_uint4(0u, 0u, 0u, 0u);
            if (m0 == 0) {
                uint32_t u0 = (uint32_t)f2bf(wls[kq2 * 8 + 0]) | ((uint32_t)f2bf(wls[kq2 * 8 + 1]) << 16);
                uint32_t u1 = (uint32_t)f2bf(wls[kq2 * 8 + 2]) | ((uint32_t)f2bf(wls[kq2 * 8 + 3]) << 16);
                uint32_t u2 = (uint32_t)f2bf(wls[kq2 * 8 + 4]) | ((uint32_t)f2bf(wls[kq2 * 8 + 5]) << 16);
                uint32_t u3 = (uint32_t)f2bf(wls[kq2 * 8 + 6]) | ((uint32_t)f2bf(wls[kq2 * 8 + 7]) << 16);
                val = make_uint4(u0, u1, u2, u3);
            }
            *reinterpret_cast<uint4*>(whBo + ((size_t)(ig * 9 + 8) * 64 + t) * 8) = val;
        }
    }
}

// ---- KMAIN v9: LDS-staged, double-buffered (unchanged; T measured = 24.1us) ----
__global__ __launch_bounds__(256) void k_agg(const uint32_t* __restrict__ adjb,
                                             const unsigned short* __restrict__ whB,
                                             float* __restrict__ P) {
    __shared__ __align__(16) unsigned short Bs[2][36 * 512];   // 2 x 36,864 B
    __shared__ __align__(16) uint32_t Ab[2][512];              // 2 x  2,048 B

    int t = threadIdx.x;
    int w = t >> 6, lane = t & 63;
    int m = lane & 15, kq = lane >> 4;
    int blk = blockIdx.x;
    int bigrs = blk >> 3, ksplit = blk & 7;       // 64 rowsets x 8 ksplits
    int rb = bigrs * 128;
    int w32 = w * 32;
    uint32_t sh = (uint32_t)kq * 8;

    float4v acc[2][9];
    #pragma unroll
    for (int s = 0; s < 2; s++)
        for (int c = 0; c < 9; c++) acc[s][c] = (float4v)0.0f;

    auto stage = [&](int ph, int b) {
        const unsigned short* gB = whB + (size_t)(ksplit * 32 + ph * 4) * 9 * 512;
        #pragma unroll
        for (int s = 0; s < 9; s++)
            gl_lds16(gB + (size_t)(s * 256 + t) * 8, &Bs[b][(s * 256 + t) * 8]);
        if (t < 128)
            gl_lds16(adjb + (size_t)(rb + t) * 256 + ksplit * 32 + ph * 4, &Ab[b][t * 4]);
    };

    stage(0, 0);
    __syncthreads();

    for (int ph = 0; ph < 8; ph++) {
        int b = ph & 1;
        if (ph < 7) stage(ph + 1, b ^ 1);
        const unsigned short* bs = &Bs[b][0];
        const uint32_t* ab = &Ab[b][0];
        #pragma unroll
        for (int i4 = 0; i4 < 4; i4++) {
            uint32_t U0 = ab[(w32 + m) * 4 + i4];
            uint32_t U1 = ab[(w32 + 16 + m) * 4 + i4];
            short8 af0 = expand8((U0 >> sh) & 0xFFu);
            short8 af1 = expand8((U1 >> sh) & 0xFFu);
            #pragma unroll
            for (int c = 0; c < 9; c++) {
                short8 bf = *reinterpret_cast<const short8*>(&bs[(i4 * 9 + c) * 512 + lane * 8]);
                acc[0][c] = __builtin_amdgcn_mfma_f32_16x16x32_bf16(af0, bf, acc[0][c], 0, 0, 0);
                acc[1][c] = __builtin_amdgcn_mfma_f32_16x16x32_bf16(af1, bf, acc[1][c], 0, 0, 0);
            }
        }
        __syncthreads();
    }

    int wid = blk * 4 + w;                        // 0..2047
    float* o = P + (size_t)wid * 4608 + lane;
    #pragma unroll
    for (int s = 0; s < 2; s++)
        for (int c = 0; c < 9; c++)
            for (int rr = 0; rr < 4; rr++)
                o[((s * 9 + c) * 4 + rr) * 64] = acc[s][c][rr];
}

// ---- reduce 8 ksplit-partials + divide. PROBE: x16 in-kernel reps ----
__global__ __launch_bounds__(256) void k_epi(const float* __restrict__ P,
                                             float* __restrict__ out) {
    __shared__ float den[32];
    int t = threadIdx.x;
    int g = blockIdx.x;                           // 32-row rowset
    int big = g >> 2, w = g & 3;

    #pragma unroll 1
    for (int rep = 0; rep < 16; rep++) {
        const float* Po = P;
        float* outo = out;
        asm volatile("" : "+v"(Po), "+v"(outo));  // opaque per rep
        __syncthreads();                          // prev rep's den readers done

        float r[18];
        #pragma unroll
        for (int i = 0; i < 18; i++) {
            int p = t + 256 * i;
            float s = 0.0f;
            #pragma unroll
            for (int ks = 0; ks < 8; ks++)
                s += Po[(size_t)((big * 8 + ks) * 4 + w) * 4608 + p];
            r[i] = s;
            int instr = p >> 6, lane = p & 63;
            int sc = instr >> 2, rr = instr & 3;
            int c = sc % 9, ss = sc / 9;
            int m = lane & 15, kq = lane >> 4;
            if (c == 8 && m == 0) den[ss * 16 + kq * 4 + rr] = s;
        }
        __syncthreads();
        #pragma unroll
        for (int i = 0; i < 18; i++) {
            int p = t + 256 * i;
            int instr = p >> 6, lane = p & 63;
            int sc = instr >> 2, rr = instr & 3;
            int c = sc % 9, ss = sc / 9;
            int m = lane & 15, kq = lane >> 4;
            if (c < 8) {
                int jl = ss * 16 + kq * 4 + rr;
                outo[((size_t)(g * 32 + jl)) * 128 + c * 16 + m] = r[i] / den[jl];
            }
        }
    }
}

extern "C" void kernel_launch(void* const* d_in, const int* in_sizes, int n_in,
                              void* d_out, int out_size, void* d_ws, size_t ws_size,
                              hipStream_t stream) {
    const float* F   = (const float*)d_in[0];     // [8192][256]
    const int*   adj = (const int*)d_in[1];       // [8192][8192] 0/1
    const float* W   = (const float*)d_in[2];     // [256][128]
    const float* bv  = (const float*)d_in[3];     // [128]
    const float* a2w = (const float*)d_in[6];     // [128]  (a1 cancels; d_in[4],[5] unused)
    const float* a2b = (const float*)d_in[7];     // [1]
    float* out = (float*)d_out;                   // [8192][128]

    char* ws = (char*)d_ws;
    unsigned short* whB  = (unsigned short*)(ws);            //  2,359,296 B
    uint32_t*       adjb = (uint32_t*)(ws + 2359296);        //  8,388,608 B
    float*          P    = (float*)(ws + 10747904);          // 37,748,736 B (2048 x 4608 fp32)
                                                             // total 48,496,640

    k_hW<<<256, 256, 0, stream>>>(F, W, bv, a2w, a2b, whB);      // x16 in-kernel
    k_adjbits<<<4096, 256, 0, stream>>>(adj, adjb);              // x8 in-kernel
    k_agg<<<512, 256, 0, stream>>>(adjb, whB, P);                // x1 (T=24.1us)
    k_epi<<<256, 256, 0, stream>>>(P, out);                      // x16 in-kernel
}

// Round 10
// 522.655 us; speedup vs baseline: 2.5439x; 2.5439x over previous
//
#include <hip/hip_runtime.h>
#include <hip/hip_bf16.h>
#include <stdint.h>

// GAT forward, N=8192, IN=256, OUT=128. Inputs fp32 (adj int32), output fp32.
// softmax_j(a1_i + a2_j | adj) == adj_ij*exp(a2_j)/sum_j adj_ij*exp(a2_j)  (a1 cancels)
// -> out = (adj @ (w*h)) / (adj @ w), with w=exp(h.a2w+a2b), h=F@W+b.
// v12b: fuse epi into agg (last-block-per-rowset tail). Attribution ledger
// (R7 agg x4 probe, R8 rep-probe): t_hW~25 (LDS-conflict-bound, 8e7 conflicts),
// t_agg=24.1, t_adjbits+t_epi ~220 -- both far above floors (45/7us), both
// latency/boundary-bound, invisible to top-5 (<158us fill cutoff). Killing the
// epi kernel boundary hides its 37.7MB reduction under remaining agg blocks'
// MFMA and drops a launch. R9's container failure audited as infra (no
// spin-waits -> no deadlock; bounds verified); resubmit with one hardening:
// tail block self-resets ctr[bigrs]=0 (rocprof kernel-replay idempotence).
//   k_hW:      h/w/whB VALU kernel (unchanged).
//   k_adjbits: adj int32 -> 8 MB bitmask + zero ctr[64].
//   k_agg:     LDS-staged bitmask x whB -> P; last block of each 128-row rowset
//              reduces 8 ksplits + divides -> out; resets its ctr slot.

typedef __attribute__((ext_vector_type(8))) short short8;
typedef __attribute__((ext_vector_type(4))) float float4v;

static __device__ __forceinline__ unsigned short f2bf(float f) {
    union { float f; uint32_t i; } v; v.f = f;
    uint32_t r = v.i + 0x7FFFu + ((v.i >> 16) & 1u);
    return (unsigned short)(r >> 16);
}

// round fp32 to bf16 precision, keep as fp32 (matches MFMA-bf16 numerics)
static __device__ __forceinline__ float bfr(float x) {
    union { float f; uint32_t u; } v; v.f = x;
    uint32_t r = (v.u + 0x7FFFu + ((v.u >> 16) & 1u)) & 0xFFFF0000u;
    union { uint32_t u; float f; } o; o.u = r;
    return o.f;
}

// expand 8 bits -> 8 packed bf16 {0.0, 1.0}.
static __device__ __forceinline__ short8 expand8(uint32_t B) {
    uint64_t S = ((uint64_t)B * 0x8040201008040201ull >> 7) & 0x0101010101010101ull;
    uint32_t lo = (uint32_t)S;          // bytes {b7,b6,b5,b4}
    uint32_t hi = (uint32_t)(S >> 32);  // bytes {b3,b2,b1,b0}
    union { uint32_t u[4]; short8 s; } r;
    r.u[0] = ((hi >> 24) | (((hi >> 16) & 0xFFu) << 16)) * 0x3F80u;  // e0,e1
    r.u[1] = (((hi >> 8) & 0xFFu) | ((hi & 0xFFu) << 16)) * 0x3F80u; // e2,e3
    r.u[2] = ((lo >> 24) | (((lo >> 16) & 0xFFu) << 16)) * 0x3F80u;  // e4,e5
    r.u[3] = (((lo >> 8) & 0xFFu) | ((lo & 0xFFu) << 16)) * 0x3F80u; // e6,e7
    return r.s;
}

// async global->LDS, 16 B per lane. LDS dest is (wave-uniform base + lane*16).
static __device__ __forceinline__ void gl_lds16(const void* g, void* l) {
    __builtin_amdgcn_global_load_lds(
        (const __attribute__((address_space(1))) uint32_t*)g,
        (__attribute__((address_space(3))) uint32_t*)l, 16, 0, 0);
}

// ---- prepass: adj int32 -> bitmask; also zero the rowset counters ----
__global__ __launch_bounds__(256) void k_adjbits(const int* __restrict__ adj,
                                                 uint32_t* __restrict__ adjb,
                                                 int* __restrict__ ctr) {
    int t = threadIdx.x, lane = t & 63;
    if (blockIdx.x == 0 && t < 64) ctr[t] = 0;
    int wv = blockIdx.x * 4 + (t >> 6);           // 0..16383
    int row = wv >> 1, half = wv & 1;
    const int4* p = reinterpret_cast<const int4*>(adj + (size_t)row * 8192 + half * 4096) + lane;
    uint32_t* ob = adjb + (size_t)row * 256 + half * 128;
    #pragma unroll 4
    for (int kk = 0; kk < 16; kk++) {
        int4 v = p[kk * 64];
        uint32_t nib = (v.x != 0 ? 1u : 0u) | (v.y != 0 ? 2u : 0u) |
                       (v.z != 0 ? 4u : 0u) | (v.w != 0 ? 8u : 0u);
        uint32_t q = nib | (((uint32_t)__shfl_xor((int)nib, 1)) << 4);
        q |= ((uint32_t)__shfl_xor((int)q, 2)) << 8;
        q |= ((uint32_t)__shfl_xor((int)q, 4)) << 16;
        if ((lane & 7) == 0) ob[kk * 8 + (lane >> 3)] = q;
    }
}

// ---- h = F@W+b, w = exp(h.a2w+a2b), emit fragment-major whB ----
__global__ __launch_bounds__(256) void k_hW(const float* __restrict__ F,
                                            const float* __restrict__ W,
                                            const float* __restrict__ bvec,
                                            const float* __restrict__ a2w,
                                            const float* __restrict__ a2b,
                                            unsigned short* __restrict__ whB) {
    __shared__ float Fs[32 * 256];     // 32 KB
    __shared__ float Ws[64 * 128];     // 32 KB (one kt-chunk of W)
    __shared__ float bs[128], aws[128], wls[32];
    __shared__ float ab_s;

    int t = threadIdx.x;
    int row = t >> 3, g = t & 7;
    int ig = blockIdx.x, j0 = ig * 32;

    if (t < 128) { bs[t] = bvec[t]; aws[t] = a2w[t]; }
    if (t == 0) ab_s = a2b[0];

    #pragma unroll
    for (int i = 0; i < 8; i++) {
        int flat = t + 256 * i;                   // float4 index
        int fr = flat >> 6, fp_ = (flat & 63) << 2;
        float4 v = *reinterpret_cast<const float4*>(F + (size_t)(j0 + fr) * 256 + fp_);
        float4 o; o.x = bfr(v.x); o.y = bfr(v.y); o.z = bfr(v.z); o.w = bfr(v.w);
        *reinterpret_cast<float4*>(&Fs[fr * 256 + fp_]) = o;
    }

    float h[16];
    #pragma unroll
    for (int i = 0; i < 16; i++) h[i] = 0.0f;

    for (int kt = 0; kt < 4; kt++) {
        if (kt) __syncthreads();
        #pragma unroll
        for (int i = 0; i < 8; i++) {
            int flat = t + 256 * i;
            int wr = flat >> 5, wp = (flat & 31) << 2;
            float4 v = *reinterpret_cast<const float4*>(W + (size_t)(kt * 64 + wr) * 128 + wp);
            float4 o; o.x = bfr(v.x); o.y = bfr(v.y); o.z = bfr(v.z); o.w = bfr(v.w);
            *reinterpret_cast<float4*>(&Ws[wr * 128 + wp]) = o;
        }
        __syncthreads();
        for (int kk = 0; kk < 64; kk++) {
            float f = Fs[row * 256 + kt * 64 + kk];
            #pragma unroll
            for (int i = 0; i < 16; i++)
                h[i] += f * Ws[kk * 128 + g * 16 + i];
        }
    }

    float part = 0.0f;
    #pragma unroll
    for (int i = 0; i < 16; i++) {
        h[i] += bs[g * 16 + i];
        part += h[i] * aws[g * 16 + i];
    }
    part += __shfl_xor(part, 1);
    part += __shfl_xor(part, 2);
    part += __shfl_xor(part, 4);
    float wv = expf(fminf(fmaxf(part + ab_s, -60.0f), 60.0f));
    if (g == 0) wls[row] = wv;

    // whB record (ig,c): lane l=(kq,m), elem r holds B[k=ig*32+kq*8+r][col=c*16+m].
    int kq = row >> 3, r = row & 7;
    #pragma unroll
    for (int i = 0; i < 16; i++) {
        unsigned short u = f2bf(h[i] * wv);
        whB[((size_t)(ig * 9 + g) * 64 + kq * 16 + i) * 8 + r] = u;
    }
    __syncthreads();
    if (t < 64) {
        int m0 = t & 15, kq2 = t >> 4;
        uint4 val = make_uint4(0u, 0u, 0u, 0u);
        if (m0 == 0) {
            uint32_t u0 = (uint32_t)f2bf(wls[kq2 * 8 + 0]) | ((uint32_t)f2bf(wls[kq2 * 8 + 1]) << 16);
            uint32_t u1 = (uint32_t)f2bf(wls[kq2 * 8 + 2]) | ((uint32_t)f2bf(wls[kq2 * 8 + 3]) << 16);
            uint32_t u2 = (uint32_t)f2bf(wls[kq2 * 8 + 4]) | ((uint32_t)f2bf(wls[kq2 * 8 + 5]) << 16);
            uint32_t u3 = (uint32_t)f2bf(wls[kq2 * 8 + 6]) | ((uint32_t)f2bf(wls[kq2 * 8 + 7]) << 16);
            val = make_uint4(u0, u1, u2, u3);
        }
        *reinterpret_cast<uint4*>(whB + ((size_t)(ig * 9 + 8) * 64 + t) * 8) = val;
    }
}

// ---- KMAIN v12b: LDS-staged agg + fused last-block reduction/divide ----
// 512 blocks (64 rowsets x 8 ksplits) x 4 waves; block = 128 rows x K-chunk 1024.
// After P stores: threadfence + atomicAdd(ctr[bigrs]); 8th arriver acquires,
// reduces the rowset's 8 partials + divides -> out, then resets ctr slot.
__global__ __launch_bounds__(256) void k_agg(const uint32_t* __restrict__ adjb,
                                             const unsigned short* __restrict__ whB,
                                             float* __restrict__ P,
                                             int* __restrict__ ctr,
                                             float* __restrict__ out) {
    __shared__ __align__(16) unsigned short Bs[2][36 * 512];   // 2 x 36,864 B
    __shared__ __align__(16) uint32_t Ab[2][512];              // 2 x  2,048 B
    __shared__ float den[32];
    __shared__ int done_s;

    int t = threadIdx.x;
    int w = t >> 6, lane = t & 63;
    int m = lane & 15, kq = lane >> 4;
    int blk = blockIdx.x;
    int bigrs = blk >> 3, ksplit = blk & 7;       // 64 rowsets x 8 ksplits
    int rb = bigrs * 128;
    int w32 = w * 32;
    uint32_t sh = (uint32_t)kq * 8;

    float4v acc[2][9];
    #pragma unroll
    for (int s = 0; s < 2; s++)
        for (int c = 0; c < 9; c++) acc[s][c] = (float4v)0.0f;

    auto stage = [&](int ph, int b) {
        const unsigned short* gB = whB + (size_t)(ksplit * 32 + ph * 4) * 9 * 512;
        #pragma unroll
        for (int s = 0; s < 9; s++)
            gl_lds16(gB + (size_t)(s * 256 + t) * 8, &Bs[b][(s * 256 + t) * 8]);
        if (t < 128)
            gl_lds16(adjb + (size_t)(rb + t) * 256 + ksplit * 32 + ph * 4, &Ab[b][t * 4]);
    };

    stage(0, 0);
    __syncthreads();

    for (int ph = 0; ph < 8; ph++) {
        int b = ph & 1;
        if (ph < 7) stage(ph + 1, b ^ 1);
        const unsigned short* bs = &Bs[b][0];
        const uint32_t* ab = &Ab[b][0];
        #pragma unroll
        for (int i4 = 0; i4 < 4; i4++) {
            uint32_t U0 = ab[(w32 + m) * 4 + i4];
            uint32_t U1 = ab[(w32 + 16 + m) * 4 + i4];
            short8 af0 = expand8((U0 >> sh) & 0xFFu);
            short8 af1 = expand8((U1 >> sh) & 0xFFu);
            #pragma unroll
            for (int c = 0; c < 9; c++) {
                short8 bf = *reinterpret_cast<const short8*>(&bs[(i4 * 9 + c) * 512 + lane * 8]);
                acc[0][c] = __builtin_amdgcn_mfma_f32_16x16x32_bf16(af0, bf, acc[0][c], 0, 0, 0);
                acc[1][c] = __builtin_amdgcn_mfma_f32_16x16x32_bf16(af1, bf, acc[1][c], 0, 0, 0);
            }
        }
        __syncthreads();
    }

    int wid = blk * 4 + w;                        // 0..2047
    float* o = P + (size_t)wid * 4608 + lane;
    #pragma unroll
    for (int s = 0; s < 2; s++)
        for (int c = 0; c < 9; c++)
            for (int rr = 0; rr < 4; rr++)
                o[((s * 9 + c) * 4 + rr) * 64] = acc[s][c][rr];

    // ---- last-block-per-rowset tail: reduce 8 ksplits + divide -> out ----
    __threadfence();                              // release: P stores visible device-wide
    if (t == 0) done_s = atomicAdd(&ctr[bigrs], 1);
    __syncthreads();
    if (done_s != 7) return;                      // uniform branch (LDS-broadcast)
    __threadfence();                              // acquire: other blocks' P stores
    if (t == 0) ctr[bigrs] = 0;                   // self-reset (replay idempotence)

    for (int ww = 0; ww < 4; ww++) {              // 4 wave-rows of 32 = 128 rows
        float r[18];
        #pragma unroll
        for (int i = 0; i < 18; i++) {
            int f = t + 256 * i;                  // [0, 4608)
            float s = 0.0f;
            #pragma unroll
            for (int ks = 0; ks < 8; ks++)
                s += P[(size_t)((bigrs * 8 + ks) * 4 + ww) * 4608 + f];
            r[i] = s;
            int instr = f >> 6, ln = f & 63;
            int ss = (instr >= 36) ? 1 : 0, c = (instr % 36) >> 2, rr = instr & 3;
            int mm = ln & 15, kk2 = ln >> 4;
            if (c == 8 && mm == 0) den[ss * 16 + kk2 * 4 + rr] = s;
        }
        __syncthreads();
        #pragma unroll
        for (int i = 0; i < 18; i++) {
            int f = t + 256 * i;
            int instr = f >> 6, ln = f & 63;
            int ss = (instr >= 36) ? 1 : 0, c = (instr % 36) >> 2, rr = instr & 3;
            int mm = ln & 15, kk2 = ln >> 4;
            if (c < 8) {
                int jl = ss * 16 + kk2 * 4 + rr;
                out[((size_t)(rb + ww * 32 + jl)) * 128 + c * 16 + mm] = r[i] / den[jl];
            }
        }
        __syncthreads();                          // den reuse guard
    }
}

extern "C" void kernel_launch(void* const* d_in, const int* in_sizes, int n_in,
                              void* d_out, int out_size, void* d_ws, size_t ws_size,
                              hipStream_t stream) {
    const float* F   = (const float*)d_in[0];     // [8192][256]
    const int*   adj = (const int*)d_in[1];       // [8192][8192] 0/1
    const float* W   = (const float*)d_in[2];     // [256][128]
    const float* bv  = (const float*)d_in[3];     // [128]
    const float* a2w = (const float*)d_in[6];     // [128]  (a1 cancels; d_in[4],[5] unused)
    const float* a2b = (const float*)d_in[7];     // [1]
    float* out = (float*)d_out;                   // [8192][128]

    char* ws = (char*)d_ws;
    unsigned short* whB  = (unsigned short*)(ws);            //  2,359,296 B
    uint32_t*       adjb = (uint32_t*)(ws + 2359296);        //  8,388,608 B
    float*          P    = (float*)(ws + 10747904);          // 37,748,736 B (2048 x 4608 fp32)
    int*            ctr  = (int*)(ws + 48496640);            //        256 B (64 counters)
                                                             // total 48,496,896

    k_hW<<<256, 256, 0, stream>>>(F, W, bv, a2w, a2b, whB);
    k_adjbits<<<4096, 256, 0, stream>>>(adj, adjb, ctr);
    k_agg<<<512, 256, 0, stream>>>(adjb, whB, P, ctr, out);
}

// Round 11
// 405.743 us; speedup vs baseline: 3.2769x; 1.2881x over previous
//
#include <hip/hip_runtime.h>
#include <hip/hip_bf16.h>
#include <stdint.h>

// GAT forward, N=8192, IN=256, OUT=128. Inputs fp32 (adj int32), output fp32.
// softmax_j(a1_i + a2_j | adj) == adj_ij*exp(a2_j)/sum_j adj_ij*exp(a2_j)  (a1 cancels)
// -> out = (adj @ (w*h)) / (adj @ w), with w=exp(h.a2w+a2b), h=F@W+b.
// v13: revert R10's fence-fused tail (device-scope __threadfence on gfx950 =
// per-XCD L2 writeback; 512 serialized flushes cost ~+100us, k_agg ballooned to
// 160us @ 10% occupancy). Back to v9's fence-free pipeline, plus two changes:
//  (1) k_front: hW and adjbits merged into ONE kernel (blocks 0-255 = hW,
//      256-4351 = adjbits) -- independent work, same stream can't overlap two
//      kernels, but one kernel's blocks co-schedule; hW (~25us) hides under the
//      268 MB adjbits stream. hW drops its Fs LDS tile (read F via L1 -- also
//      kills the 8e7 bank conflicts measured in R8, which came from Fs's
//      stride-256 row reads) so LDS = 33 KB -> 4 blocks/CU for adjbits blocks.
//  (2) k_epi v2: 512 blocks (rowset x half), float4 loads/stores, 24 fully
//      independent loads/thread. Same ks-ascending sum order -> bit-identical.
//   k_agg: v9 LDS-staged double-buffered kernel, byte-identical (24us warm).

typedef __attribute__((ext_vector_type(8))) short short8;
typedef __attribute__((ext_vector_type(4))) float float4v;

static __device__ __forceinline__ unsigned short f2bf(float f) {
    union { float f; uint32_t i; } v; v.f = f;
    uint32_t r = v.i + 0x7FFFu + ((v.i >> 16) & 1u);
    return (unsigned short)(r >> 16);
}

// round fp32 to bf16 precision, keep as fp32 (matches MFMA-bf16 numerics)
static __device__ __forceinline__ float bfr(float x) {
    union { float f; uint32_t u; } v; v.f = x;
    uint32_t r = (v.u + 0x7FFFu + ((v.u >> 16) & 1u)) & 0xFFFF0000u;
    union { uint32_t u; float f; } o; o.u = r;
    return o.f;
}

// expand 8 bits -> 8 packed bf16 {0.0, 1.0}.
static __device__ __forceinline__ short8 expand8(uint32_t B) {
    uint64_t S = ((uint64_t)B * 0x8040201008040201ull >> 7) & 0x0101010101010101ull;
    uint32_t lo = (uint32_t)S;          // bytes {b7,b6,b5,b4}
    uint32_t hi = (uint32_t)(S >> 32);  // bytes {b3,b2,b1,b0}
    union { uint32_t u[4]; short8 s; } r;
    r.u[0] = ((hi >> 24) | (((hi >> 16) & 0xFFu) << 16)) * 0x3F80u;  // e0,e1
    r.u[1] = (((hi >> 8) & 0xFFu) | ((hi & 0xFFu) << 16)) * 0x3F80u; // e2,e3
    r.u[2] = ((lo >> 24) | (((lo >> 16) & 0xFFu) << 16)) * 0x3F80u;  // e4,e5
    r.u[3] = (((lo >> 8) & 0xFFu) | ((lo & 0xFFu) << 16)) * 0x3F80u; // e6,e7
    return r.s;
}

// async global->LDS, 16 B per lane. LDS dest is (wave-uniform base + lane*16).
static __device__ __forceinline__ void gl_lds16(const void* g, void* l) {
    __builtin_amdgcn_global_load_lds(
        (const __attribute__((address_space(1))) uint32_t*)g,
        (__attribute__((address_space(3))) uint32_t*)l, 16, 0, 0);
}

// ---- k_front: blocks 0-255 = hW (h,w,whB); blocks 256-4351 = adjbits ----
__global__ __launch_bounds__(256) void k_front(const float* __restrict__ F,
                                               const float* __restrict__ W,
                                               const float* __restrict__ bvec,
                                               const float* __restrict__ a2w,
                                               const float* __restrict__ a2b,
                                               unsigned short* __restrict__ whB,
                                               const int* __restrict__ adj,
                                               uint32_t* __restrict__ adjb) {
    int t = threadIdx.x;

    if (blockIdx.x >= 256) {
        // ---------------- adjbits: adj int32 -> bitmask ----------------
        int lane = t & 63;
        int wv = (blockIdx.x - 256) * 4 + (t >> 6);   // 0..16383
        int row = wv >> 1, half = wv & 1;
        const int4* p = reinterpret_cast<const int4*>(adj + (size_t)row * 8192 + half * 4096) + lane;
        uint32_t* ob = adjb + (size_t)row * 256 + half * 128;
        #pragma unroll 4
        for (int kk = 0; kk < 16; kk++) {
            int4 v = p[kk * 64];
            uint32_t nib = (v.x != 0 ? 1u : 0u) | (v.y != 0 ? 2u : 0u) |
                           (v.z != 0 ? 4u : 0u) | (v.w != 0 ? 8u : 0u);
            uint32_t q = nib | (((uint32_t)__shfl_xor((int)nib, 1)) << 4);
            q |= ((uint32_t)__shfl_xor((int)q, 2)) << 8;
            q |= ((uint32_t)__shfl_xor((int)q, 4)) << 16;
            if ((lane & 7) == 0) ob[kk * 8 + (lane >> 3)] = q;
        }
        return;
    }

    // ---------------- hW: h = F@W+b, w = exp(h.a2w+a2b), whB ----------------
    __shared__ float Ws[64 * 128];     // 32 KB (one kt-chunk of W, bf16-rounded)
    __shared__ float bs[128], aws[128], wls[32];
    __shared__ float ab_s;

    int row = t >> 3, g = t & 7;
    int ig = blockIdx.x, j0 = ig * 32;

    if (t < 128) { bs[t] = bvec[t]; aws[t] = a2w[t]; }
    if (t == 0) ab_s = a2b[0];

    const float* frow = F + (size_t)(j0 + row) * 256;  // L1-resident (32 KB/block)

    float h[16];
    #pragma unroll
    for (int i = 0; i < 16; i++) h[i] = 0.0f;

    for (int kt = 0; kt < 4; kt++) {
        if (kt) __syncthreads();
        #pragma unroll
        for (int i = 0; i < 8; i++) {                  // stage W chunk, bfr'd once
            int flat = t + 256 * i;
            int wr = flat >> 5, wp = (flat & 31) << 2;
            float4 v = *reinterpret_cast<const float4*>(W + (size_t)(kt * 64 + wr) * 128 + wp);
            float4 o; o.x = bfr(v.x); o.y = bfr(v.y); o.z = bfr(v.z); o.w = bfr(v.w);
            *reinterpret_cast<float4*>(&Ws[wr * 128 + wp]) = o;
        }
        __syncthreads();
        for (int kk = 0; kk < 64; kk++) {
            float f = bfr(frow[kt * 64 + kk]);
            #pragma unroll
            for (int i = 0; i < 16; i++)
                h[i] += f * Ws[kk * 128 + g * 16 + i];
        }
    }

    float part = 0.0f;
    #pragma unroll
    for (int i = 0; i < 16; i++) {
        h[i] += bs[g * 16 + i];
        part += h[i] * aws[g * 16 + i];
    }
    part += __shfl_xor(part, 1);
    part += __shfl_xor(part, 2);
    part += __shfl_xor(part, 4);
    float wv = expf(fminf(fmaxf(part + ab_s, -60.0f), 60.0f));
    if (g == 0) wls[row] = wv;

    // whB record (ig,c): lane l=(kq,m), elem r holds B[k=ig*32+kq*8+r][col=c*16+m].
    int kq = row >> 3, r = row & 7;
    #pragma unroll
    for (int i = 0; i < 16; i++) {
        unsigned short u = f2bf(h[i] * wv);
        whB[((size_t)(ig * 9 + g) * 64 + kq * 16 + i) * 8 + r] = u;
    }
    __syncthreads();
    if (t < 64) {
        int m0 = t & 15, kq2 = t >> 4;
        uint4 val = make_uint4(0u, 0u, 0u, 0u);
        if (m0 == 0) {
            uint32_t u0 = (uint32_t)f2bf(wls[kq2 * 8 + 0]) | ((uint32_t)f2bf(wls[kq2 * 8 + 1]) << 16);
            uint32_t u1 = (uint32_t)f2bf(wls[kq2 * 8 + 2]) | ((uint32_t)f2bf(wls[kq2 * 8 + 3]) << 16);
            uint32_t u2 = (uint32_t)f2bf(wls[kq2 * 8 + 4]) | ((uint32_t)f2bf(wls[kq2 * 8 + 5]) << 16);
            uint32_t u3 = (uint32_t)f2bf(wls[kq2 * 8 + 6]) | ((uint32_t)f2bf(wls[kq2 * 8 + 7]) << 16);
            val = make_uint4(u0, u1, u2, u3);
        }
        *reinterpret_cast<uint4*>(whB + ((size_t)(ig * 9 + 8) * 64 + t) * 8) = val;
    }
}

// ---- KMAIN v9 (byte-identical to R6): LDS-staged, double-buffered ----
// 512 blocks (64 rowsets x 8 ksplits) x 4 waves; block = 128 rows x K-chunk 1024.
__global__ __launch_bounds__(256) void k_agg(const uint32_t* __restrict__ adjb,
                                             const unsigned short* __restrict__ whB,
                                             float* __restrict__ P) {
    __shared__ __align__(16) unsigned short Bs[2][36 * 512];   // 2 x 36,864 B
    __shared__ __align__(16) uint32_t Ab[2][512];              // 2 x  2,048 B

    int t = threadIdx.x;
    int w = t >> 6, lane = t & 63;
    int m = lane & 15, kq = lane >> 4;
    int blk = blockIdx.x;
    int bigrs = blk >> 3, ksplit = blk & 7;       // 64 rowsets x 8 ksplits
    int rb = bigrs * 128;
    int w32 = w * 32;
    uint32_t sh = (uint32_t)kq * 8;

    float4v acc[2][9];
    #pragma unroll
    for (int s = 0; s < 2; s++)
        for (int c = 0; c < 9; c++) acc[s][c] = (float4v)0.0f;

    auto stage = [&](int ph, int b) {
        const unsigned short* gB = whB + (size_t)(ksplit * 32 + ph * 4) * 9 * 512;
        #pragma unroll
        for (int s = 0; s < 9; s++)
            gl_lds16(gB + (size_t)(s * 256 + t) * 8, &Bs[b][(s * 256 + t) * 8]);
        if (t < 128)
            gl_lds16(adjb + (size_t)(rb + t) * 256 + ksplit * 32 + ph * 4, &Ab[b][t * 4]);
    };

    stage(0, 0);
    __syncthreads();

    for (int ph = 0; ph < 8; ph++) {
        int b = ph & 1;
        if (ph < 7) stage(ph + 1, b ^ 1);
        const unsigned short* bs = &Bs[b][0];
        const uint32_t* ab = &Ab[b][0];
        #pragma unroll
        for (int i4 = 0; i4 < 4; i4++) {
            uint32_t U0 = ab[(w32 + m) * 4 + i4];
            uint32_t U1 = ab[(w32 + 16 + m) * 4 + i4];
            short8 af0 = expand8((U0 >> sh) & 0xFFu);
            short8 af1 = expand8((U1 >> sh) & 0xFFu);
            #pragma unroll
            for (int c = 0; c < 9; c++) {
                short8 bf = *reinterpret_cast<const short8*>(&bs[(i4 * 9 + c) * 512 + lane * 8]);
                acc[0][c] = __builtin_amdgcn_mfma_f32_16x16x32_bf16(af0, bf, acc[0][c], 0, 0, 0);
                acc[1][c] = __builtin_amdgcn_mfma_f32_16x16x32_bf16(af1, bf, acc[1][c], 0, 0, 0);
            }
        }
        __syncthreads();
    }

    int wid = blk * 4 + w;                        // 0..2047
    float* o = P + (size_t)wid * 4608 + lane;
    #pragma unroll
    for (int s = 0; s < 2; s++)
        for (int c = 0; c < 9; c++)
            for (int rr = 0; rr < 4; rr++)
                o[((s * 9 + c) * 4 + rr) * 64] = acc[s][c][rr];
}

// ---- epi v2: reduce 8 ksplit-partials + divide. 512 blocks x 256 thr. ----
// Block b = (g = 32-row rowset, ss = 16-row half). Each wid's [ss*2304, +2304)
// slice is contiguous -> float4 loads. Same ks-ascending sum order as v9.
__global__ __launch_bounds__(256) void k_epi(const float* __restrict__ P,
                                             float* __restrict__ out) {
    __shared__ float den[16];
    int t = threadIdx.x;
    int b = blockIdx.x;
    int g = b >> 1, ss = b & 1;
    int big = g >> 2, w = g & 3;
    const float* base = P + (size_t)(big * 32 + w) * 4608 + ss * 2304;

    int fo0 = 4 * t, fo1 = 1024 + 4 * t, fo2 = 2048 + 4 * t;   // fo2 valid for t<64
    float4 r0 = make_float4(0.f, 0.f, 0.f, 0.f);
    float4 r1 = make_float4(0.f, 0.f, 0.f, 0.f);
    float4 r2 = make_float4(0.f, 0.f, 0.f, 0.f);
    #pragma unroll
    for (int ks = 0; ks < 8; ks++) {               // ks stride = 4 wids = 18432 floats
        const float* bp = base + (size_t)ks * 18432;
        float4 a = *reinterpret_cast<const float4*>(bp + fo0);
        float4 c = *reinterpret_cast<const float4*>(bp + fo1);
        r0.x += a.x; r0.y += a.y; r0.z += a.z; r0.w += a.w;
        r1.x += c.x; r1.y += c.y; r1.z += c.z; r1.w += c.w;
        if (t < 64) {
            float4 d = *reinterpret_cast<const float4*>(bp + fo2);
            r2.x += d.x; r2.y += d.y; r2.z += d.z; r2.w += d.w;
        }
    }
    // fo2 block is entirely c==8 (den column): li=32+(t>>4), m=(4t)&15.
    if (t < 64 && (t & 3) == 0)
        den[((t >> 2) & 3) * 4 + (t >> 4)] = r2.x;  // den[kq*4 + rr]
    __syncthreads();

    {   // j=0: c in 0..3
        int li = fo0 >> 6, c = li >> 2, rr = li & 3;
        int ln = fo0 & 63, kq = ln >> 4, m = ln & 15;
        float dv = den[kq * 4 + rr];
        int rw = g * 32 + ss * 16 + kq * 4 + rr;
        float4 o = make_float4(r0.x / dv, r0.y / dv, r0.z / dv, r0.w / dv);
        *reinterpret_cast<float4*>(out + (size_t)rw * 128 + c * 16 + m) = o;
    }
    {   // j=1: c in 4..7
        int li = fo1 >> 6, c = li >> 2, rr = li & 3;
        int ln = fo1 & 63, kq = ln >> 4, m = ln & 15;
        float dv = den[kq * 4 + rr];
        int rw = g * 32 + ss * 16 + kq * 4 + rr;
        float4 o = make_float4(r1.x / dv, r1.y / dv, r1.z / dv, r1.w / dv);
        *reinterpret_cast<float4*>(out + (size_t)rw * 128 + c * 16 + m) = o;
    }
}

extern "C" void kernel_launch(void* const* d_in, const int* in_sizes, int n_in,
                              void* d_out, int out_size, void* d_ws, size_t ws_size,
                              hipStream_t stream) {
    const float* F   = (const float*)d_in[0];     // [8192][256]
    const int*   adj = (const int*)d_in[1];       // [8192][8192] 0/1
    const float* W   = (const float*)d_in[2];     // [256][128]
    const float* bv  = (const float*)d_in[3];     // [128]
    const float* a2w = (const float*)d_in[6];     // [128]  (a1 cancels; d_in[4],[5] unused)
    const float* a2b = (const float*)d_in[7];     // [1]
    float* out = (float*)d_out;                   // [8192][128]

    char* ws = (char*)d_ws;
    unsigned short* whB  = (unsigned short*)(ws);            //  2,359,296 B
    uint32_t*       adjb = (uint32_t*)(ws + 2359296);        //  8,388,608 B
    float*          P    = (float*)(ws + 10747904);          // 37,748,736 B (2048 x 4608 fp32)
                                                             // total 48,496,640

    k_front<<<4352, 256, 0, stream>>>(F, W, bv, a2w, a2b, whB, adj, adjb);
    k_agg<<<512, 256, 0, stream>>>(adjb, whB, P);
    k_epi<<<512, 256, 0, stream>>>(P, out);
}